// Round 3
// baseline (125335.522 us; speedup 1.0000x reference)
//
#include <hip/hip_runtime.h>
#include <hip/hip_bf16.h>
#include <math.h>

#define BDIM 512
#define TDIM 1024
#define UDIM 512
#define NG   2048   // 4*U

typedef __attribute__((ext_vector_type(8))) short short8;
typedef __attribute__((ext_vector_type(4))) float float4v;

// ---------------- workspace layout ----------------
#define OFF_U0T   ((size_t)0)                       // bf16 [2048][512]  gate-interleaved, transposed
#define SZ_U0T    ((size_t)NG*UDIM*2)
#define OFF_W1U1T (OFF_U0T + SZ_U0T)                // bf16 [2048][1024] (W1 k<512, U1 k>=512)
#define SZ_W1U1T  ((size_t)NG*1024*2)
#define OFF_W0P   (OFF_W1U1T + SZ_W1U1T)            // f32 [3][2048] permuted
#define SZ_W0P    ((size_t)3*NG*4)
#define OFF_B0P   (OFF_W0P + SZ_W0P)
#define OFF_B1P   (OFF_B0P + (size_t)NG*4)
#define OFF_STATE (OFF_B1P + (size_t)NG*4)
#define SZ_HB     ((size_t)BDIM*UDIM*2)
#define SZ_HF     ((size_t)BDIM*UDIM*4)
#define OFF_H0B   (OFF_STATE)                       // bf16 x2 ping-pong
#define OFF_H1B   (OFF_H0B + 2*SZ_HB)
#define OFF_H0F   (OFF_H1B + 2*SZ_HB)               // f32 master x2
#define OFF_H1F   (OFF_H0F + 2*SZ_HF)
#define OFF_C0    (OFF_H1F + 2*SZ_HF)
#define OFF_C1    (OFF_C0 + SZ_HF)
#define OFF_BAR   (OFF_C1 + SZ_HF)                  // barrier: 8 group ctrs (128B apart) + root
#define SZ_BAR    ((size_t)(8*32+32)*4)
#define STATE_BYTES (OFF_BAR + SZ_BAR - OFF_STATE)

#define NBLK 192          // 64 l0 (first 8 also do FC) + 128 l1; 24 blocks per barrier group
#define L1_BASE 64

__device__ __forceinline__ float fsigm(float x) {
    return __builtin_amdgcn_rcpf(1.0f + __expf(-x));
}
__device__ __forceinline__ float ftanh(float x) {
    // tanh(x) = 1 - 2/(1+e^{2x}) ; |abs err| ~3e-7, overflow-safe
    return 1.0f - 2.0f * __builtin_amdgcn_rcpf(1.0f + __expf(2.0f * x));
}

__device__ __forceinline__ void async_ld16(const void* g, void* l) {
    __builtin_amdgcn_global_load_lds(
        (const __attribute__((address_space(1))) unsigned int*)g,
        (__attribute__((address_space(3))) unsigned int*)l, 16, 0, 0);
}

// ---------- weight prep (proven in r1): transpose + gate-interleave ----------
// n' = unit*4 + gate  <-  orig col = gate*512 + unit
__global__ void prep_kernel(const float* __restrict__ W0, const float* __restrict__ U0,
                            const float* __restrict__ b0, const float* __restrict__ W1,
                            const float* __restrict__ U1, const float* __restrict__ b1,
                            char* __restrict__ ws)
{
    int idx = blockIdx.x * 256 + threadIdx.x;   // 2048*1024 total
    int n = idx >> 10;
    int k = idx & 1023;
    int oc = (n & 3) * UDIM + (n >> 2);
    __hip_bfloat16* U0t = (__hip_bfloat16*)(ws + OFF_U0T);
    __hip_bfloat16* Wc  = (__hip_bfloat16*)(ws + OFF_W1U1T);
    float* W0p = (float*)(ws + OFF_W0P);
    float* b0p = (float*)(ws + OFF_B0P);
    float* b1p = (float*)(ws + OFF_B1P);
    if (k < 512) U0t[(size_t)n * 512 + k] = __float2bfloat16(U0[(size_t)k * NG + oc]);
    float wv = (k < 512) ? W1[(size_t)k * NG + oc] : U1[(size_t)(k - 512) * NG + oc];
    Wc[(size_t)n * 1024 + k] = __float2bfloat16(wv);
    if (k < 3) W0p[k * NG + n] = W0[(size_t)k * NG + oc];
    if (k == 0) { b0p[n] = b0[oc]; b1p[n] = b1[oc]; }
}

// ---------- two-level grid barrier (192 blocks = 8 groups x 24) ----------
__device__ __forceinline__ void gridbar(unsigned* bar, unsigned phase, int blk) {
    __syncthreads();
    if (threadIdx.x == 0) {
        unsigned* gc   = bar + (blk & 7) * 32;
        unsigned* root = bar + 256;
        __threadfence();   // release: drain + make prior writes globally visible
        unsigned prev = __hip_atomic_fetch_add(gc, 1u, __ATOMIC_ACQ_REL, __HIP_MEMORY_SCOPE_AGENT);
        if (prev + 1u == phase * 24u)
            __hip_atomic_fetch_add(root, 1u, __ATOMIC_ACQ_REL, __HIP_MEMORY_SCOPE_AGENT);
        while (__hip_atomic_load(root, __ATOMIC_ACQUIRE, __HIP_MEMORY_SCOPE_AGENT) < phase * 8u) {}
        __threadfence();   // acquire: invalidate stale cached lines
    }
    __syncthreads();
}

// ---------- fused LSTM gate + phased time-gate (one unit, one batch row) ----------
__device__ __forceinline__ void gate_update(float4v z, int b, int u, int t, bool isL0,
    const float* __restrict__ bias, const float* __restrict__ W0p,
    const float* __restrict__ inputs, const float* __restrict__ times,
    const float* __restrict__ tau, const float* __restrict__ sph,
    float* __restrict__ cst, const float* __restrict__ hf_prev,
    float* __restrict__ hf_cur, __hip_bfloat16* __restrict__ hb_cur)
{
    int pc = u * 4;
    float4v bz = *(const float4v*)&bias[pc];
    float zi = z[0] + bz[0], zf = z[1] + bz[1], zg = z[2] + bz[2], zo = z[3] + bz[3];
    if (isL0) {
        const float* xp = &inputs[((size_t)b * TDIM + t) * 3];
        float x0 = xp[0], x1 = xp[1], x2 = xp[2];
        float4v w0 = *(const float4v*)&W0p[pc];
        float4v w1 = *(const float4v*)&W0p[NG + pc];
        float4v w2 = *(const float4v*)&W0p[2 * NG + pc];
        zi += x0 * w0[0] + x1 * w1[0] + x2 * w2[0];
        zf += x0 * w0[1] + x1 * w1[1] + x2 * w2[1];
        zg += x0 * w0[2] + x1 * w1[2] + x2 * w2[2];
        zo += x0 * w0[3] + x1 * w1[3] + x2 * w2[3];
    }
    float ig = fsigm(zi), fg = fsigm(zf), gg = ftanh(zg), og = fsigm(zo);
    size_t su = (size_t)b * UDIM + u;
    float cp = cst[su];
    float cc = fg * cp + ig * gg;
    float hc = og * ftanh(cc);
    float tt = times[(size_t)b * TDIM + t];
    float x = (tt - sph[u]) / tau[u];
    float ph = x - floorf(x);                       // == mod(t-s,tau)/tau in [0,1)
    float kg = (ph < 0.025f) ? (ph * 40.0f)
             : (ph < 0.05f ? 2.0f - ph * 40.0f : 0.001f * ph);
    float cn = kg * cc + (1.0f - kg) * cp;
    float hn = kg * hc + (1.0f - kg) * hf_prev[su];
    cst[su] = cn;
    hf_cur[su] = hn;
    hb_cur[su] = __float2bfloat16(hn);
}

// ---------- layer-0 step: 128x128 tile, K=512, A&B streamed+dbuf ----------
__device__ __forceinline__ void l0_step(char* smem, int mtile, int ntile, int t,
    const short* __restrict__ A0, const short* __restrict__ Wt,
    const float* __restrict__ bias, const float* __restrict__ W0p,
    const float* __restrict__ inputs, const float* __restrict__ times,
    const float* __restrict__ tau, const float* __restrict__ sph,
    float* __restrict__ cst, const float* __restrict__ hf_prev,
    float* __restrict__ hf_cur, __hip_bfloat16* __restrict__ hb_cur)
{
    const int tid = threadIdx.x, wave = tid >> 6, lane = tid & 63;
    const int lr = lane & 15, lq = lane >> 4;
    const int wr = (wave & 1) * 64, wc = (wave >> 1) * 64;
    short* sB = (short*)smem;                  // 2 x [128][32] shorts (16 KB)
    short* sA = (short*)(smem + 16384);        // 2 x [128][32] shorts (16 KB)
    const int srow = lane >> 2;                // 0..15 in 16-row slab
    const int scol = (lane & 3) * 8;
    const int arow = mtile * 128 + wave * 32 + srow;
    const int brow = ntile * 128 + wave * 32 + srow;
    const int lbase = wave * 1024;             // shorts: 32 rows * 32/slab-pair

    const float4v zero4 = {0.0f, 0.0f, 0.0f, 0.0f};
    float4v acc[4][4];
#pragma unroll
    for (int i = 0; i < 4; ++i)
#pragma unroll
        for (int j = 0; j < 4; ++j) acc[i][j] = zero4;

    // prologue: chunk 0 -> buf 0 (gridbar's trailing __syncthreads precedes us)
    async_ld16(A0 + (size_t)arow * 512 + scol,        sA + lbase);
    async_ld16(A0 + (size_t)(arow + 16) * 512 + scol, sA + lbase + 512);
    async_ld16(Wt + (size_t)brow * 512 + scol,        sB + lbase);
    async_ld16(Wt + (size_t)(brow + 16) * 512 + scol, sB + lbase + 512);

    for (int c = 0; c < 16; ++c) {
        const int buf = (c & 1) * 4096;
        __syncthreads();                       // drains vmcnt -> chunk c resident
        if (c < 15) {
            const int nb = buf ^ 4096;
            const int kk = (c + 1) * 32;
            async_ld16(A0 + (size_t)arow * 512 + kk + scol,        sA + nb + lbase);
            async_ld16(A0 + (size_t)(arow + 16) * 512 + kk + scol, sA + nb + lbase + 512);
            async_ld16(Wt + (size_t)brow * 512 + kk + scol,        sB + nb + lbase);
            async_ld16(Wt + (size_t)(brow + 16) * 512 + kk + scol, sB + nb + lbase + 512);
        }
        short8 aF[4], bF[4];
#pragma unroll
        for (int i = 0; i < 4; ++i) aF[i] = *(const short8*)&sA[buf + (wr + i * 16 + lr) * 32 + lq * 8];
#pragma unroll
        for (int j = 0; j < 4; ++j) bF[j] = *(const short8*)&sB[buf + (wc + j * 16 + lr) * 32 + lq * 8];
#pragma unroll
        for (int i = 0; i < 4; ++i)
#pragma unroll
            for (int j = 0; j < 4; ++j)
                acc[i][j] = __builtin_amdgcn_mfma_f32_16x16x32_bf16(aF[i], bF[j], acc[i][j], 0, 0, 0);
    }

    // epilogue: 8 chunks of 16 perm-cols (4 units) via LDS transpose
    float* Z = (float*)smem;                   // [128][20] f32 (10 KB, aliases sB)
    for (int ch = 0; ch < 8; ++ch) {
        __syncthreads();
        if ((ch >> 2) == (wave >> 1)) {
            int j = ch & 3;
#pragma unroll
            for (int i = 0; i < 4; ++i)
#pragma unroll
                for (int r = 0; r < 4; ++r)
                    Z[(wr + i * 16 + lq * 4 + r) * 20 + lr] = acc[i][j][r];
        }
        __syncthreads();
#pragma unroll
        for (int it = 0; it < 2; ++it) {
            int q = it * 256 + tid;            // 0..511
            int row = q >> 2, ui = q & 3;
            float4v z = *(const float4v*)&Z[row * 20 + ui * 4];
            gate_update(z, mtile * 128 + row, ntile * 32 + ch * 4 + ui, t, true,
                        bias, W0p, inputs, times, tau, sph, cst, hf_prev, hf_cur, hb_cur);
        }
    }
}

// ---------- layer-1 step: 128x64 tile, K=1024 (A = [h0 | h1]), A&B streamed ----------
__device__ __forceinline__ void l1_step(char* smem, int mtile, int ntile, int t,
    const short* __restrict__ A0, const short* __restrict__ A1,
    const short* __restrict__ Wt, const float* __restrict__ bias,
    const float* __restrict__ inputs, const float* __restrict__ times,
    const float* __restrict__ tau, const float* __restrict__ sph,
    float* __restrict__ cst, const float* __restrict__ hf_prev,
    float* __restrict__ hf_cur, __hip_bfloat16* __restrict__ hb_cur)
{
    const int tid = threadIdx.x, wave = tid >> 6, lane = tid & 63;
    const int lr = lane & 15, lq = lane >> 4;
    const int wr = (wave & 1) * 64, wc = (wave >> 1) * 32;
    short* sB = (short*)smem;                  // 2 x [64][32] shorts (8 KB)
    short* sA = (short*)(smem + 8192);         // 2 x [128][32] shorts (16 KB)
    const int srow = lane >> 2;
    const int scol = (lane & 3) * 8;
    const int arow = mtile * 128 + wave * 32 + srow;
    const int brow = ntile * 64 + wave * 16 + srow;
    const int labase = wave * 1024;
    const int lbbase = wave * 512;

    const float4v zero4 = {0.0f, 0.0f, 0.0f, 0.0f};
    float4v acc[4][2];
#pragma unroll
    for (int i = 0; i < 4; ++i)
#pragma unroll
        for (int j = 0; j < 2; ++j) acc[i][j] = zero4;

    // prologue: chunk 0 -> buf 0
    async_ld16(A0 + (size_t)arow * 512 + scol,        sA + labase);
    async_ld16(A0 + (size_t)(arow + 16) * 512 + scol, sA + labase + 512);
    async_ld16(Wt + (size_t)brow * 1024 + scol,       sB + lbbase);

    for (int c = 0; c < 32; ++c) {
        const int bufA = (c & 1) * 4096;
        const int bufB = (c & 1) * 2048;
        __syncthreads();
        if (c < 31) {
            const int cc = c + 1;
            const short* base = (cc < 16) ? A0 : A1;
            const int kk = (cc & 15) * 32;
            async_ld16(base + (size_t)arow * 512 + kk + scol,        sA + (bufA ^ 4096) + labase);
            async_ld16(base + (size_t)(arow + 16) * 512 + kk + scol, sA + (bufA ^ 4096) + labase + 512);
            async_ld16(Wt + (size_t)brow * 1024 + cc * 32 + scol,    sB + (bufB ^ 2048) + lbbase);
        }
        short8 aF[4], bF[2];
#pragma unroll
        for (int i = 0; i < 4; ++i) aF[i] = *(const short8*)&sA[bufA + (wr + i * 16 + lr) * 32 + lq * 8];
#pragma unroll
        for (int j = 0; j < 2; ++j) bF[j] = *(const short8*)&sB[bufB + (wc + j * 16 + lr) * 32 + lq * 8];
#pragma unroll
        for (int i = 0; i < 4; ++i)
#pragma unroll
            for (int j = 0; j < 2; ++j)
                acc[i][j] = __builtin_amdgcn_mfma_f32_16x16x32_bf16(aF[i], bF[j], acc[i][j], 0, 0, 0);
    }

    // epilogue: 4 chunks of 16 perm-cols
    float* Z = (float*)smem;                   // [128][20] f32
    for (int ch = 0; ch < 4; ++ch) {
        __syncthreads();
        if ((ch >> 1) == (wave >> 1)) {
            int j = ch & 1;
#pragma unroll
            for (int i = 0; i < 4; ++i)
#pragma unroll
                for (int r = 0; r < 4; ++r)
                    Z[(wr + i * 16 + lq * 4 + r) * 20 + lr] = acc[i][j][r];
        }
        __syncthreads();
#pragma unroll
        for (int it = 0; it < 2; ++it) {
            int q = it * 256 + tid;
            int row = q >> 2, ui = q & 3;
            float4v z = *(const float4v*)&Z[row * 20 + ui * 4];
            gate_update(z, mtile * 128 + row, ntile * 16 + ch * 4 + ui, t, false,
                        bias, nullptr, inputs, times, tau, sph, cst, hf_prev, hf_cur, hb_cur);
        }
    }
}

// ---------- FC + softmax for 64 batch rows ----------
__device__ __forceinline__ void fc_step(int fcid, int t, const float* __restrict__ h,
    const float* __restrict__ Wfc, const float* __restrict__ bfc, float* __restrict__ out)
{
    int wave = threadIdx.x >> 6, lane = threadIdx.x & 63;
    int rbase = fcid * 64 + wave * 16;
    for (int ri = 0; ri < 16; ++ri) {
        int row = rbase + ri;
        float a[10];
#pragma unroll
        for (int c = 0; c < 10; ++c) a[c] = 0.0f;
        for (int it = 0; it < 8; ++it) {
            float hv = h[(size_t)row * UDIM + it * 64 + lane];
            const float* wp = &Wfc[(size_t)(it * 64 + lane) * 10];
#pragma unroll
            for (int c = 0; c < 10; ++c) a[c] += hv * wp[c];
        }
#pragma unroll
        for (int c = 0; c < 10; ++c)
            for (int m = 32; m; m >>= 1) a[c] += __shfl_xor(a[c], m, 64);
        if (lane == 0) {
            float mx = -1e30f;
#pragma unroll
            for (int c = 0; c < 10; ++c) { a[c] += bfc[c]; mx = fmaxf(mx, a[c]); }
            float sum = 0.0f;
#pragma unroll
            for (int c = 0; c < 10; ++c) { a[c] = __expf(a[c] - mx); sum += a[c]; }
            float inv = 1.0f / sum;
            float* op = &out[((size_t)row * TDIM + t) * 10];
#pragma unroll
            for (int c = 0; c < 10; ++c) op[c] = a[c] * inv;
        }
    }
}

// ---------- persistent diagonal-wavefront kernel, regular launch ----------
__global__ __launch_bounds__(256, 2)
void persist_kernel(const float* __restrict__ inputs, const float* __restrict__ times,
                    const float* __restrict__ tau0, const float* __restrict__ sp0,
                    const float* __restrict__ tau1, const float* __restrict__ sp1,
                    const float* __restrict__ Wfc, const float* __restrict__ bfc,
                    char* __restrict__ ws, float* __restrict__ out)
{
    __shared__ __align__(16) char smem[32768];
    const int blk = blockIdx.x;

    __hip_bfloat16* h0b[2] = {(__hip_bfloat16*)(ws + OFF_H0B), (__hip_bfloat16*)(ws + OFF_H0B + SZ_HB)};
    __hip_bfloat16* h1b[2] = {(__hip_bfloat16*)(ws + OFF_H1B), (__hip_bfloat16*)(ws + OFF_H1B + SZ_HB)};
    float* h0f[2] = {(float*)(ws + OFF_H0F), (float*)(ws + OFF_H0F + SZ_HF)};
    float* h1f[2] = {(float*)(ws + OFF_H1F), (float*)(ws + OFF_H1F + SZ_HF)};
    float* c0 = (float*)(ws + OFF_C0);
    float* c1 = (float*)(ws + OFF_C1);
    unsigned* bar = (unsigned*)(ws + OFF_BAR);
    const float* b0p = (const float*)(ws + OFF_B0P);
    const float* b1p = (const float*)(ws + OFF_B1P);
    const float* W0p = (const float*)(ws + OFF_W0P);
    const short* U0t = (const short*)(ws + OFF_U0T);
    const short* Wc  = (const short*)(ws + OFF_W1U1T);

    for (int s = 0; s < TDIM + 2; ++s) {
        const int pA = (s + 1) & 1;   // parity holding step s-1 data
        const int pB = s & 1;         // parity holding step s-2 / receiving step s
        if (blk < L1_BASE) {
            if (s < TDIM)
                l0_step(smem, blk >> 4, blk & 15, s,
                        (const short*)h0b[pA], U0t, b0p, W0p, inputs, times, tau0, sp0,
                        c0, h0f[pA], h0f[pB], h0b[pB]);
            if (blk < 8 && s >= 2)
                fc_step(blk, s - 2, h1f[pB], Wfc, bfc, out);
        } else {
            if (s >= 1 && s <= TDIM)
                l1_step(smem, (blk - L1_BASE) >> 5, (blk - L1_BASE) & 31, s - 1,
                        (const short*)h0b[pA], (const short*)h1b[pB], Wc, b1p,
                        inputs, times, tau1, sp1,
                        c1, h1f[pB], h1f[pA], h1b[pA]);
        }
        gridbar(bar, (unsigned)(s + 1), blk);
    }
}

extern "C" void kernel_launch(void* const* d_in, const int* in_sizes, int n_in,
                              void* d_out, int out_size, void* d_ws, size_t ws_size,
                              hipStream_t stream) {
    const float* inputs = (const float*)d_in[0];
    const float* times  = (const float*)d_in[1];
    const float* W0   = (const float*)d_in[2];
    const float* U0   = (const float*)d_in[3];
    const float* b0   = (const float*)d_in[4];
    const float* tau0 = (const float*)d_in[5];
    const float* s0v  = (const float*)d_in[6];
    const float* W1   = (const float*)d_in[7];
    const float* U1   = (const float*)d_in[8];
    const float* b1   = (const float*)d_in[9];
    const float* tau1 = (const float*)d_in[10];
    const float* s1v  = (const float*)d_in[11];
    const float* Wfc  = (const float*)d_in[12];
    const float* bfc  = (const float*)d_in[13];
    float* out = (float*)d_out;
    char* ws = (char*)d_ws;

    hipMemsetAsync(ws + OFF_STATE, 0, STATE_BYTES, stream);
    prep_kernel<<<(NG * 1024) / 256, 256, 0, stream>>>(W0, U0, b0, W1, U1, b1, ws);
    persist_kernel<<<NBLK, 256, 0, stream>>>(inputs, times, tau0, s0v, tau1, s1v,
                                             Wfc, bfc, ws, out);
}

// Round 4
// 82465.240 us; speedup vs baseline: 1.5199x; 1.5199x over previous
//
#include <hip/hip_runtime.h>
#include <hip/hip_bf16.h>
#include <math.h>

#define BDIM 512
#define TDIM 1024
#define UDIM 512
#define NG   2048   // 4*U

typedef __attribute__((ext_vector_type(8))) short short8;
typedef __attribute__((ext_vector_type(4))) float float4v;

// ---------------- workspace layout ----------------
#define OFF_U0T   ((size_t)0)                       // bf16 [2048][512]  gate-interleaved, transposed
#define SZ_U0T    ((size_t)NG*UDIM*2)
#define OFF_W1U1T (OFF_U0T + SZ_U0T)                // bf16 [2048][1024] (W1 k<512, U1 k>=512)
#define SZ_W1U1T  ((size_t)NG*1024*2)
#define OFF_W0P   (OFF_W1U1T + SZ_W1U1T)            // f32 [3][2048] permuted
#define SZ_W0P    ((size_t)3*NG*4)
#define OFF_B0P   (OFF_W0P + SZ_W0P)
#define OFF_B1P   (OFF_B0P + (size_t)NG*4)
#define OFF_STATE (OFF_B1P + (size_t)NG*4)
#define SZ_HB     ((size_t)BDIM*UDIM*2)
#define SZ_HF     ((size_t)BDIM*UDIM*4)
#define OFF_H0B   (OFF_STATE)                       // bf16 x2 ping-pong
#define OFF_H1B   (OFF_H0B + 2*SZ_HB)
#define OFF_H0F   (OFF_H1B + 2*SZ_HB)               // f32 master x2
#define OFF_H1F   (OFF_H0F + 2*SZ_HF)
#define OFF_C0    (OFF_H1F + 2*SZ_HF)
#define OFF_C1    (OFF_C0 + SZ_HF)
#define OFF_BAR   (OFF_C1 + SZ_HF)                  // barrier: 8 group ctrs (128B apart) + root
#define SZ_BAR    ((size_t)(8*32+32)*4)
#define STATE_BYTES (OFF_BAR + SZ_BAR - OFF_STATE)

#define NBLK 208          // 64 l0 + 128 l1 + 16 fc ; 8 barrier groups x 26
#define L1_BASE 64
#define FC_BASE 192

__device__ __forceinline__ float fsigm(float x) {
    return __builtin_amdgcn_rcpf(1.0f + __expf(-x));
}
__device__ __forceinline__ float ftanh(float x) {
    return 1.0f - 2.0f * __builtin_amdgcn_rcpf(1.0f + __expf(2.0f * x));
}

// ---------- weight prep (proven r1/r3): transpose + gate-interleave ----------
// n' = unit*4 + gate  <-  orig col = gate*512 + unit
__global__ void prep_kernel(const float* __restrict__ W0, const float* __restrict__ U0,
                            const float* __restrict__ b0, const float* __restrict__ W1,
                            const float* __restrict__ U1, const float* __restrict__ b1,
                            char* __restrict__ ws)
{
    int idx = blockIdx.x * 256 + threadIdx.x;   // 2048*1024 total
    int n = idx >> 10;
    int k = idx & 1023;
    int oc = (n & 3) * UDIM + (n >> 2);
    __hip_bfloat16* U0t = (__hip_bfloat16*)(ws + OFF_U0T);
    __hip_bfloat16* Wc  = (__hip_bfloat16*)(ws + OFF_W1U1T);
    float* W0p = (float*)(ws + OFF_W0P);
    float* b0p = (float*)(ws + OFF_B0P);
    float* b1p = (float*)(ws + OFF_B1P);
    if (k < 512) U0t[(size_t)n * 512 + k] = __float2bfloat16(U0[(size_t)k * NG + oc]);
    float wv = (k < 512) ? W1[(size_t)k * NG + oc] : U1[(size_t)(k - 512) * NG + oc];
    Wc[(size_t)n * 1024 + k] = __float2bfloat16(wv);
    if (k < 3) W0p[k * NG + n] = W0[(size_t)k * NG + oc];
    if (k == 0) { b0p[n] = b0[oc]; b1p[n] = b1[oc]; }
}

// ---------- two-level grid barrier (208 blocks = 8 groups x 26) ----------
__device__ __forceinline__ void gridbar(unsigned* bar, unsigned phase, int blk) {
    __syncthreads();
    if (threadIdx.x == 0) {
        unsigned* gc   = bar + (blk & 7) * 32;
        unsigned* root = bar + 256;
        __threadfence();   // release: make prior writes globally visible (L2 wb)
        unsigned prev = __hip_atomic_fetch_add(gc, 1u, __ATOMIC_ACQ_REL, __HIP_MEMORY_SCOPE_AGENT);
        if (prev + 1u == phase * 26u)
            __hip_atomic_fetch_add(root, 1u, __ATOMIC_ACQ_REL, __HIP_MEMORY_SCOPE_AGENT);
        while (__hip_atomic_load(root, __ATOMIC_ACQUIRE, __HIP_MEMORY_SCOPE_AGENT) < phase * 8u) {}
        __threadfence();   // acquire: invalidate stale cached lines
    }
    __syncthreads();
}

// ---------- fused LSTM gate + phased time-gate (one unit, one batch row) ----------
__device__ __forceinline__ void gate_update(float4v z, int b, int u, int t, bool isL0,
    const float* __restrict__ bias, const float* __restrict__ W0p,
    const float* __restrict__ inputs, const float* __restrict__ times,
    const float* __restrict__ tau, const float* __restrict__ sph,
    float* __restrict__ cst, const float* __restrict__ hf_prev,
    float* __restrict__ hf_cur, __hip_bfloat16* __restrict__ hb_cur)
{
    int pc = u * 4;
    float4v bz = *(const float4v*)&bias[pc];
    float zi = z[0] + bz[0], zf = z[1] + bz[1], zg = z[2] + bz[2], zo = z[3] + bz[3];
    if (isL0) {
        const float* xp = &inputs[((size_t)b * TDIM + t) * 3];
        float x0 = xp[0], x1 = xp[1], x2 = xp[2];
        float4v w0 = *(const float4v*)&W0p[pc];
        float4v w1 = *(const float4v*)&W0p[NG + pc];
        float4v w2 = *(const float4v*)&W0p[2 * NG + pc];
        zi += x0 * w0[0] + x1 * w1[0] + x2 * w2[0];
        zf += x0 * w0[1] + x1 * w1[1] + x2 * w2[1];
        zg += x0 * w0[2] + x1 * w1[2] + x2 * w2[2];
        zo += x0 * w0[3] + x1 * w1[3] + x2 * w2[3];
    }
    float ig = fsigm(zi), fg = fsigm(zf), gg = ftanh(zg), og = fsigm(zo);
    size_t su = (size_t)b * UDIM + u;
    float cp = cst[su];
    float cc = fg * cp + ig * gg;
    float hc = og * ftanh(cc);
    float tt = times[(size_t)b * TDIM + t];
    float x = (tt - sph[u]) / tau[u];
    float ph = x - floorf(x);                       // == mod(t-s,tau)/tau in [0,1)
    float kg = (ph < 0.025f) ? (ph * 40.0f)
             : (ph < 0.05f ? 2.0f - ph * 40.0f : 0.001f * ph);
    float cn = kg * cc + (1.0f - kg) * cp;
    float hn = kg * hc + (1.0f - kg) * hf_prev[su];
    cst[su] = cn;
    hf_cur[su] = hn;
    hb_cur[su] = __float2bfloat16(hn);
}

// ---------- layer-0 step: 128x128 tile, K=512; direct global frag loads, depth-3 ----------
__device__ __forceinline__ void l0_step(char* smem, int mtile, int ntile, int t,
    const short* __restrict__ A0, const short* __restrict__ Wt,
    const float* __restrict__ bias, const float* __restrict__ W0p,
    const float* __restrict__ inputs, const float* __restrict__ times,
    const float* __restrict__ tau, const float* __restrict__ sph,
    float* __restrict__ cst, const float* __restrict__ hf_prev,
    float* __restrict__ hf_cur, __hip_bfloat16* __restrict__ hb_cur)
{
    const int tid = threadIdx.x, wave = tid >> 6, lane = tid & 63;
    const int lr = lane & 15, lq = lane >> 4;
    const int wr = (wave & 1) * 64, wc = (wave >> 1) * 64;
    // lane's fragment base: A[m=row][k], row stride 512; 4 lq-lanes cover a 64B line
    const short* Ab = A0 + (size_t)(mtile * 128 + wr + lr) * 512 + lq * 8;
    const short* Bb = Wt + (size_t)(ntile * 128 + wc + lr) * 512 + lq * 8;

    const float4v zero4 = {0.0f, 0.0f, 0.0f, 0.0f};
    float4v acc[4][4];
#pragma unroll
    for (int i = 0; i < 4; ++i)
#pragma unroll
        for (int j = 0; j < 4; ++j) acc[i][j] = zero4;

    short8 aP[3][4], bP[3][4];
#pragma unroll
    for (int c = 0; c < 3; ++c)
#pragma unroll
        for (int i = 0; i < 4; ++i) {
            aP[c][i] = *(const short8*)(Ab + i * 16 * 512 + c * 32);
            bP[c][i] = *(const short8*)(Bb + i * 16 * 512 + c * 32);
        }
#pragma unroll
    for (int c = 0; c < 16; ++c) {
        const int s3 = c % 3;
#pragma unroll
        for (int i = 0; i < 4; ++i)
#pragma unroll
            for (int j = 0; j < 4; ++j)
                acc[i][j] = __builtin_amdgcn_mfma_f32_16x16x32_bf16(aP[s3][i], bP[s3][j], acc[i][j], 0, 0, 0);
        if (c + 3 < 16) {
#pragma unroll
            for (int i = 0; i < 4; ++i) {
                aP[s3][i] = *(const short8*)(Ab + i * 16 * 512 + (c + 3) * 32);
                bP[s3][i] = *(const short8*)(Bb + i * 16 * 512 + (c + 3) * 32);
            }
        }
    }

    // epilogue: 2 passes of 64 perm-cols via LDS transpose
    float* Z = (float*)smem;                   // [128][68] f32 = 34816 B
#pragma unroll
    for (int p = 0; p < 2; ++p) {
        __syncthreads();
        if ((wave >> 1) == p) {
#pragma unroll
            for (int i = 0; i < 4; ++i)
#pragma unroll
                for (int j = 0; j < 4; ++j)
#pragma unroll
                    for (int r = 0; r < 4; ++r)
                        Z[(wr + i * 16 + lq * 4 + r) * 68 + (j * 16 + lr)] = acc[i][j][r];
        }
        __syncthreads();
#pragma unroll
        for (int rep = 0; rep < 8; ++rep) {
            int q = rep * 256 + tid;           // 0..2047
            int row = q >> 4, ui = q & 15;
            float4v z = *(const float4v*)&Z[row * 68 + ui * 4];
            gate_update(z, mtile * 128 + row, ntile * 32 + p * 16 + ui, t, true,
                        bias, W0p, inputs, times, tau, sph, cst, hf_prev, hf_cur, hb_cur);
        }
    }
}

// ---------- layer-1 step: 128x64 tile, K=1024 (A=[h0|h1]); direct frag loads ----------
__device__ __forceinline__ void l1_step(char* smem, int mtile, int ntile, int t,
    const short* __restrict__ A0, const short* __restrict__ A1,
    const short* __restrict__ Wt, const float* __restrict__ bias,
    const float* __restrict__ inputs, const float* __restrict__ times,
    const float* __restrict__ tau, const float* __restrict__ sph,
    float* __restrict__ cst, const float* __restrict__ hf_prev,
    float* __restrict__ hf_cur, __hip_bfloat16* __restrict__ hb_cur)
{
    const int tid = threadIdx.x, wave = tid >> 6, lane = tid & 63;
    const int lr = lane & 15, lq = lane >> 4;
    const int wr = (wave & 1) * 64, wc = (wave >> 1) * 32;
    const short* Ab0 = A0 + (size_t)(mtile * 128 + wr + lr) * 512 + lq * 8;
    const short* Ab1 = A1 + (size_t)(mtile * 128 + wr + lr) * 512 + lq * 8;
    const short* Bb  = Wt + (size_t)(ntile * 64 + wc + lr) * 1024 + lq * 8;

    const float4v zero4 = {0.0f, 0.0f, 0.0f, 0.0f};
    float4v acc[4][2];
#pragma unroll
    for (int i = 0; i < 4; ++i)
#pragma unroll
        for (int j = 0; j < 2; ++j) acc[i][j] = zero4;

    short8 aP[3][4], bP[3][2];
#pragma unroll
    for (int c = 0; c < 3; ++c) {
#pragma unroll
        for (int i = 0; i < 4; ++i)
            aP[c][i] = *(const short8*)(Ab0 + i * 16 * 512 + c * 32);
#pragma unroll
        for (int j = 0; j < 2; ++j)
            bP[c][j] = *(const short8*)(Bb + j * 16 * 1024 + c * 32);
    }
#pragma unroll
    for (int c = 0; c < 32; ++c) {
        const int s3 = c % 3;
#pragma unroll
        for (int i = 0; i < 4; ++i)
#pragma unroll
            for (int j = 0; j < 2; ++j)
                acc[i][j] = __builtin_amdgcn_mfma_f32_16x16x32_bf16(aP[s3][i], bP[s3][j], acc[i][j], 0, 0, 0);
        if (c + 3 < 32) {
            const int cc = c + 3;
            const short* Abase = (cc < 16) ? Ab0 : Ab1;
            const int kk = (cc & 15) * 32;
#pragma unroll
            for (int i = 0; i < 4; ++i)
                aP[s3][i] = *(const short8*)(Abase + i * 16 * 512 + kk);
#pragma unroll
            for (int j = 0; j < 2; ++j)
                bP[s3][j] = *(const short8*)(Bb + j * 16 * 1024 + cc * 32);
        }
    }

    // epilogue: 2 passes of 32 perm-cols
    float* Z = (float*)smem;                   // [128][36] f32 = 18432 B
#pragma unroll
    for (int p = 0; p < 2; ++p) {
        __syncthreads();
        if ((wave >> 1) == p) {
#pragma unroll
            for (int i = 0; i < 4; ++i)
#pragma unroll
                for (int j = 0; j < 2; ++j)
#pragma unroll
                    for (int r = 0; r < 4; ++r)
                        Z[(wr + i * 16 + lq * 4 + r) * 36 + (j * 16 + lr)] = acc[i][j][r];
        }
        __syncthreads();
#pragma unroll
        for (int rep = 0; rep < 4; ++rep) {
            int q = rep * 256 + tid;           // 0..1023
            int row = q >> 3, ui = q & 7;
            float4v z = *(const float4v*)&Z[row * 36 + ui * 4];
            gate_update(z, mtile * 128 + row, ntile * 16 + p * 8 + ui, t, false,
                        bias, nullptr, inputs, times, tau, sph, cst, hf_prev, hf_cur, hb_cur);
        }
    }
}

// ---------- FC + softmax, 32 batch rows per block; Wfc transposed in LDS ----------
__device__ __forceinline__ void fc_step(char* smem, int fcid, int t,
    const float* __restrict__ h, float* __restrict__ out)
{
    const float* wT = (const float*)smem;              // [10][512]
    const float* bl = (const float*)(smem + 20480);    // [10]
    int wave = threadIdx.x >> 6, lane = threadIdx.x & 63;
    int rbase = fcid * 32 + wave * 8;
    for (int ri = 0; ri < 8; ++ri) {
        int row = rbase + ri;
        float a[10];
#pragma unroll
        for (int c = 0; c < 10; ++c) a[c] = 0.0f;
#pragma unroll
        for (int it = 0; it < 8; ++it) {
            float hv = h[(size_t)row * UDIM + it * 64 + lane];
#pragma unroll
            for (int c = 0; c < 10; ++c) a[c] += hv * wT[c * 512 + it * 64 + lane];
        }
#pragma unroll
        for (int c = 0; c < 10; ++c)
            for (int m = 32; m; m >>= 1) a[c] += __shfl_xor(a[c], m, 64);
        if (lane == 0) {
            float mx = -1e30f;
#pragma unroll
            for (int c = 0; c < 10; ++c) { a[c] += bl[c]; mx = fmaxf(mx, a[c]); }
            float sum = 0.0f;
#pragma unroll
            for (int c = 0; c < 10; ++c) { a[c] = __expf(a[c] - mx); sum += a[c]; }
            float inv = 1.0f / sum;
            float* op = &out[((size_t)row * TDIM + t) * 10];
#pragma unroll
            for (int c = 0; c < 10; ++c) op[c] = a[c] * inv;
        }
    }
}

// ---------- persistent diagonal-wavefront kernel ----------
__global__ __launch_bounds__(256, 1)
void persist_kernel(const float* __restrict__ inputs, const float* __restrict__ times,
                    const float* __restrict__ tau0, const float* __restrict__ sp0,
                    const float* __restrict__ tau1, const float* __restrict__ sp1,
                    const float* __restrict__ Wfc, const float* __restrict__ bfc,
                    char* __restrict__ ws, float* __restrict__ out)
{
    __shared__ __align__(16) char smem[34816];
    const int blk = blockIdx.x;
    const int tid = threadIdx.x;

    __hip_bfloat16* h0b[2] = {(__hip_bfloat16*)(ws + OFF_H0B), (__hip_bfloat16*)(ws + OFF_H0B + SZ_HB)};
    __hip_bfloat16* h1b[2] = {(__hip_bfloat16*)(ws + OFF_H1B), (__hip_bfloat16*)(ws + OFF_H1B + SZ_HB)};
    float* h0f[2] = {(float*)(ws + OFF_H0F), (float*)(ws + OFF_H0F + SZ_HF)};
    float* h1f[2] = {(float*)(ws + OFF_H1F), (float*)(ws + OFF_H1F + SZ_HF)};
    float* c0 = (float*)(ws + OFF_C0);
    float* c1 = (float*)(ws + OFF_C1);
    unsigned* bar = (unsigned*)(ws + OFF_BAR);
    const float* b0p = (const float*)(ws + OFF_B0P);
    const float* b1p = (const float*)(ws + OFF_B1P);
    const float* W0p = (const float*)(ws + OFF_W0P);
    const short* U0t = (const short*)(ws + OFF_U0T);
    const short* Wc  = (const short*)(ws + OFF_W1U1T);

    if (blk >= FC_BASE) {
        // cache Wfc^T + bfc in LDS once (immune to per-step L2 invalidation)
        float* wT = (float*)smem;
        float* bl = (float*)(smem + 20480);
        for (int i = tid; i < 5120; i += 256) {
            int c = i >> 9, k = i & 511;
            wT[i] = Wfc[(size_t)k * 10 + c];
        }
        if (tid < 10) bl[tid] = bfc[tid];
        __syncthreads();
    }

    for (int s = 0; s < TDIM + 2; ++s) {
        const int pA = (s + 1) & 1;   // parity holding step s-1 data
        const int pB = s & 1;         // parity holding step s-2 / receiving step s
        if (blk < L1_BASE) {
            if (s < TDIM)
                l0_step(smem, blk >> 4, blk & 15, s,
                        (const short*)h0b[pA], U0t, b0p, W0p, inputs, times, tau0, sp0,
                        c0, h0f[pA], h0f[pB], h0b[pB]);
        } else if (blk < FC_BASE) {
            if (s >= 1 && s <= TDIM)
                l1_step(smem, (blk - L1_BASE) >> 5, (blk - L1_BASE) & 31, s - 1,
                        (const short*)h0b[pA], (const short*)h1b[pB], Wc, b1p,
                        inputs, times, tau1, sp1,
                        c1, h1f[pB], h1f[pA], h1b[pA]);
        } else {
            if (s >= 2)
                fc_step(smem, blk - FC_BASE, s - 2, h1f[pB], out);
        }
        gridbar(bar, (unsigned)(s + 1), blk);
    }
}

extern "C" void kernel_launch(void* const* d_in, const int* in_sizes, int n_in,
                              void* d_out, int out_size, void* d_ws, size_t ws_size,
                              hipStream_t stream) {
    const float* inputs = (const float*)d_in[0];
    const float* times  = (const float*)d_in[1];
    const float* W0   = (const float*)d_in[2];
    const float* U0   = (const float*)d_in[3];
    const float* b0   = (const float*)d_in[4];
    const float* tau0 = (const float*)d_in[5];
    const float* s0v  = (const float*)d_in[6];
    const float* W1   = (const float*)d_in[7];
    const float* U1   = (const float*)d_in[8];
    const float* b1   = (const float*)d_in[9];
    const float* tau1 = (const float*)d_in[10];
    const float* s1v  = (const float*)d_in[11];
    const float* Wfc  = (const float*)d_in[12];
    const float* bfc  = (const float*)d_in[13];
    float* out = (float*)d_out;
    char* ws = (char*)d_ws;

    hipMemsetAsync(ws + OFF_STATE, 0, STATE_BYTES, stream);
    prep_kernel<<<(NG * 1024) / 256, 256, 0, stream>>>(W0, U0, b0, W1, U1, b1, ws);
    persist_kernel<<<NBLK, 256, 0, stream>>>(inputs, times, tau0, s0v, tau1, s1v,
                                             Wfc, bfc, ws, out);
}

// Round 5
// 62942.499 us; speedup vs baseline: 1.9913x; 1.3102x over previous
//
#include <hip/hip_runtime.h>
#include <hip/hip_bf16.h>
#include <math.h>

#define BDIM 512
#define TDIM 1024
#define UDIM 512
#define NG   2048   // 4*U

typedef __attribute__((ext_vector_type(8))) short short8;
typedef __attribute__((ext_vector_type(4))) float float4v;

// ---------------- workspace layout ----------------
#define OFF_U0T   ((size_t)0)                       // bf16 [2048][512]  gate-interleaved, transposed
#define SZ_U0T    ((size_t)NG*UDIM*2)
#define OFF_W1U1T (OFF_U0T + SZ_U0T)                // bf16 [2048][1024] (W1 k<512, U1 k>=512)
#define SZ_W1U1T  ((size_t)NG*1024*2)
#define OFF_W0P   (OFF_W1U1T + SZ_W1U1T)            // f32 [3][2048] permuted
#define SZ_W0P    ((size_t)3*NG*4)
#define OFF_B0P   (OFF_W0P + SZ_W0P)
#define OFF_B1P   (OFF_B0P + (size_t)NG*4)
#define OFF_STATE (OFF_B1P + (size_t)NG*4)
#define SZ_HB     ((size_t)BDIM*UDIM*2)
#define SZ_HF     ((size_t)BDIM*UDIM*4)
#define OFF_H0B   (OFF_STATE)                       // bf16 x2 ping-pong
#define OFF_H1B   (OFF_H0B + 2*SZ_HB)
#define OFF_H0F   (OFF_H1B + 2*SZ_HB)               // f32 master x2
#define OFF_H1F   (OFF_H0F + 2*SZ_HF)
#define OFF_C0    (OFF_H1F + 2*SZ_HF)
#define OFF_C1    (OFF_C0 + SZ_HF)
#define OFF_BAR   (OFF_C1 + SZ_HF)                  // barrier: 8 group ctrs (128B apart) + root
#define SZ_BAR    ((size_t)(8*32+32)*4)
#define STATE_BYTES (OFF_BAR + SZ_BAR - OFF_STATE)

#define NBLK 256   // role by XCD (blk&7): x0-1 l0(64), x2-5 l1(128), x6-7 fc(32)+idle(32)

__device__ __forceinline__ float fsigm(float x) {
    return __builtin_amdgcn_rcpf(1.0f + __expf(-x));
}
__device__ __forceinline__ float ftanh(float x) {
    return 1.0f - 2.0f * __builtin_amdgcn_rcpf(1.0f + __expf(2.0f * x));
}

// coherent 16B fragment load: device-scope relaxed atomics (bypass L1/L2, read LLC)
__device__ __forceinline__ short8 ald16(const short* p) {
    union { short8 v; unsigned long long q[2]; } u;
    u.q[0] = __hip_atomic_load((const unsigned long long*)p,
                               __ATOMIC_RELAXED, __HIP_MEMORY_SCOPE_AGENT);
    u.q[1] = __hip_atomic_load((const unsigned long long*)p + 1,
                               __ATOMIC_RELAXED, __HIP_MEMORY_SCOPE_AGENT);
    return u.v;
}

// ---------- weight prep (proven r1-r4): transpose + gate-interleave ----------
// n' = unit*4 + gate  <-  orig col = gate*512 + unit
__global__ void prep_kernel(const float* __restrict__ W0, const float* __restrict__ U0,
                            const float* __restrict__ b0, const float* __restrict__ W1,
                            const float* __restrict__ U1, const float* __restrict__ b1,
                            char* __restrict__ ws)
{
    int idx = blockIdx.x * 256 + threadIdx.x;   // 2048*1024 total
    int n = idx >> 10;
    int k = idx & 1023;
    int oc = (n & 3) * UDIM + (n >> 2);
    __hip_bfloat16* U0t = (__hip_bfloat16*)(ws + OFF_U0T);
    __hip_bfloat16* Wc  = (__hip_bfloat16*)(ws + OFF_W1U1T);
    float* W0p = (float*)(ws + OFF_W0P);
    float* b0p = (float*)(ws + OFF_B0P);
    float* b1p = (float*)(ws + OFF_B1P);
    if (k < 512) U0t[(size_t)n * 512 + k] = __float2bfloat16(U0[(size_t)k * NG + oc]);
    float wv = (k < 512) ? W1[(size_t)k * NG + oc] : U1[(size_t)(k - 512) * NG + oc];
    Wc[(size_t)n * 1024 + k] = __float2bfloat16(wv);
    if (k < 3) W0p[k * NG + n] = W0[(size_t)k * NG + oc];
    if (k == 0) { b0p[n] = b0[oc]; b1p[n] = b1[oc]; }
}

// ---------- grid barrier: release-only fence (wbl2, NO L2 invalidate) ----------
__device__ __forceinline__ void gridbar(unsigned* bar, unsigned phase, int blk) {
    __syncthreads();
    if (threadIdx.x == 0) {
        unsigned* gc   = bar + (blk & 7) * 32;
        unsigned* root = bar + 256;
        // release: drain stores + write back dirty L2 lines to coherence point.
        // Crucially NOT acq_rel (__threadfence) -> no buffer_inv -> weights stay in L2.
        __builtin_amdgcn_fence(__ATOMIC_RELEASE, "agent");
        unsigned prev = __hip_atomic_fetch_add(gc, 1u, __ATOMIC_RELAXED, __HIP_MEMORY_SCOPE_AGENT);
        if (prev + 1u == phase * 32u)
            __hip_atomic_fetch_add(root, 1u, __ATOMIC_RELAXED, __HIP_MEMORY_SCOPE_AGENT);
        while (__hip_atomic_load(root, __ATOMIC_RELAXED, __HIP_MEMORY_SCOPE_AGENT) < phase * 8u) {}
        __atomic_signal_fence(__ATOMIC_ACQUIRE);  // compiler ordering; HW freshness comes from atomic state loads
    }
    __syncthreads();
}

// ---------- fused LSTM gate + phased time-gate (one unit, one batch row) ----------
__device__ __forceinline__ void gate_update(float4v z, int b, int u, int t, bool isL0,
    const float* __restrict__ bias, const float* __restrict__ W0p,
    const float* __restrict__ inputs, const float* __restrict__ times,
    const float* __restrict__ tau, const float* __restrict__ sph,
    float* __restrict__ cst, const float* __restrict__ hf_prev,
    float* __restrict__ hf_cur, __hip_bfloat16* __restrict__ hb_cur)
{
    int pc = u * 4;
    float4v bz = *(const float4v*)&bias[pc];
    float zi = z[0] + bz[0], zf = z[1] + bz[1], zg = z[2] + bz[2], zo = z[3] + bz[3];
    if (isL0) {
        const float* xp = &inputs[((size_t)b * TDIM + t) * 3];
        float x0 = xp[0], x1 = xp[1], x2 = xp[2];
        float4v w0 = *(const float4v*)&W0p[pc];
        float4v w1 = *(const float4v*)&W0p[NG + pc];
        float4v w2 = *(const float4v*)&W0p[2 * NG + pc];
        zi += x0 * w0[0] + x1 * w1[0] + x2 * w2[0];
        zf += x0 * w0[1] + x1 * w1[1] + x2 * w2[1];
        zg += x0 * w0[2] + x1 * w1[2] + x2 * w2[2];
        zo += x0 * w0[3] + x1 * w1[3] + x2 * w2[3];
    }
    float ig = fsigm(zi), fg = fsigm(zf), gg = ftanh(zg), og = fsigm(zo);
    size_t su = (size_t)b * UDIM + u;
    float cp = cst[su];
    float cc = fg * cp + ig * gg;
    float hc = og * ftanh(cc);
    float tt = times[(size_t)b * TDIM + t];
    float x = (tt - sph[u]) / tau[u];
    float ph = x - floorf(x);                       // == mod(t-s,tau)/tau in [0,1)
    float kg = (ph < 0.025f) ? (ph * 40.0f)
             : (ph < 0.05f ? 2.0f - ph * 40.0f : 0.001f * ph);
    float cn = kg * cc + (1.0f - kg) * cp;
    float hn = kg * hc + (1.0f - kg) * hf_prev[su];
    cst[su] = cn;
    hf_cur[su] = hn;
    hb_cur[su] = __float2bfloat16(hn);
}

// ---------- layer-0: 128x128 tile, K=512; depth-4 pipeline, coherent A, L2 B ----------
__device__ __forceinline__ void l0_step(char* smem, int mtile, int ntile, int t,
    const short* __restrict__ A0, const short* __restrict__ Wt,
    const float* __restrict__ bias, const float* __restrict__ W0p,
    const float* __restrict__ inputs, const float* __restrict__ times,
    const float* __restrict__ tau, const float* __restrict__ sph,
    float* __restrict__ cst, const float* __restrict__ hf_prev,
    float* __restrict__ hf_cur, __hip_bfloat16* __restrict__ hb_cur)
{
    const int tid = threadIdx.x, wave = tid >> 6, lane = tid & 63;
    const int lr = lane & 15, lq = lane >> 4;
    const int wr = (wave & 1) * 64, wc = (wave >> 1) * 64;
    const short* Ab = A0 + (size_t)(mtile * 128 + wr + lr) * 512 + lq * 8;
    const short* Bb = Wt + (size_t)(ntile * 128 + wc + lr) * 512 + lq * 8;

    const float4v zero4 = {0.0f, 0.0f, 0.0f, 0.0f};
    float4v acc[4][4];
#pragma unroll
    for (int i = 0; i < 4; ++i)
#pragma unroll
        for (int j = 0; j < 4; ++j) acc[i][j] = zero4;

    short8 aP[4][4], bP[4][4];
#pragma unroll
    for (int s = 0; s < 4; ++s)
#pragma unroll
        for (int i = 0; i < 4; ++i) {
            aP[s][i] = ald16(Ab + i * 16 * 512 + s * 32);
            bP[s][i] = *(const short8*)(Bb + i * 16 * 512 + s * 32);
        }
#pragma unroll
    for (int c = 0; c < 16; ++c) {
        const int st = c & 3;
#pragma unroll
        for (int i = 0; i < 4; ++i)
#pragma unroll
            for (int j = 0; j < 4; ++j)
                acc[i][j] = __builtin_amdgcn_mfma_f32_16x16x32_bf16(aP[st][i], bP[st][j], acc[i][j], 0, 0, 0);
        if (c + 4 < 16) {
#pragma unroll
            for (int i = 0; i < 4; ++i) {
                aP[st][i] = ald16(Ab + i * 16 * 512 + (c + 4) * 32);
                bP[st][i] = *(const short8*)(Bb + i * 16 * 512 + (c + 4) * 32);
            }
        }
    }

    // epilogue: 2 passes of 64 perm-cols via LDS transpose
    float* Z = (float*)smem;                   // [128][68] f32 = 34816 B
#pragma unroll
    for (int p = 0; p < 2; ++p) {
        __syncthreads();
        if ((wave >> 1) == p) {
#pragma unroll
            for (int i = 0; i < 4; ++i)
#pragma unroll
                for (int j = 0; j < 4; ++j)
#pragma unroll
                    for (int r = 0; r < 4; ++r)
                        Z[(wr + i * 16 + lq * 4 + r) * 68 + (j * 16 + lr)] = acc[i][j][r];
        }
        __syncthreads();
#pragma unroll
        for (int rep = 0; rep < 8; ++rep) {
            int q = rep * 256 + tid;           // 0..2047
            int row = q >> 4, ui = q & 15;
            float4v z = *(const float4v*)&Z[row * 68 + ui * 4];
            gate_update(z, mtile * 128 + row, ntile * 32 + p * 16 + ui, t, true,
                        bias, W0p, inputs, times, tau, sph, cst, hf_prev, hf_cur, hb_cur);
        }
    }
}

// ---------- layer-1: 128x64 tile, K=1024 (A=[h0|h1]); depth-4 pipeline ----------
__device__ __forceinline__ void l1_step(char* smem, int mtile, int ntile, int t,
    const short* __restrict__ A0, const short* __restrict__ A1,
    const short* __restrict__ Wt, const float* __restrict__ bias,
    const float* __restrict__ inputs, const float* __restrict__ times,
    const float* __restrict__ tau, const float* __restrict__ sph,
    float* __restrict__ cst, const float* __restrict__ hf_prev,
    float* __restrict__ hf_cur, __hip_bfloat16* __restrict__ hb_cur)
{
    const int tid = threadIdx.x, wave = tid >> 6, lane = tid & 63;
    const int lr = lane & 15, lq = lane >> 4;
    const int wr = (wave & 1) * 64, wc = (wave >> 1) * 32;
    const short* Ab0 = A0 + (size_t)(mtile * 128 + wr + lr) * 512 + lq * 8;
    const short* Ab1 = A1 + (size_t)(mtile * 128 + wr + lr) * 512 + lq * 8;
    const short* Bb  = Wt + (size_t)(ntile * 64 + wc + lr) * 1024 + lq * 8;

    const float4v zero4 = {0.0f, 0.0f, 0.0f, 0.0f};
    float4v acc[4][2];
#pragma unroll
    for (int i = 0; i < 4; ++i)
#pragma unroll
        for (int j = 0; j < 2; ++j) acc[i][j] = zero4;

    short8 aP[4][4], bP[4][2];
#pragma unroll
    for (int s = 0; s < 4; ++s) {
#pragma unroll
        for (int i = 0; i < 4; ++i)
            aP[s][i] = ald16(Ab0 + i * 16 * 512 + s * 32);
#pragma unroll
        for (int j = 0; j < 2; ++j)
            bP[s][j] = *(const short8*)(Bb + j * 16 * 1024 + s * 32);
    }
#pragma unroll
    for (int c = 0; c < 32; ++c) {
        const int st = c & 3;
#pragma unroll
        for (int i = 0; i < 4; ++i)
#pragma unroll
            for (int j = 0; j < 2; ++j)
                acc[i][j] = __builtin_amdgcn_mfma_f32_16x16x32_bf16(aP[st][i], bP[st][j], acc[i][j], 0, 0, 0);
        if (c + 4 < 32) {
            const int cc = c + 4;
            const short* Abase = (cc < 16) ? Ab0 : Ab1;
            const int kk = (cc & 15) * 32;
#pragma unroll
            for (int i = 0; i < 4; ++i)
                aP[st][i] = ald16(Abase + i * 16 * 512 + kk);
#pragma unroll
            for (int j = 0; j < 2; ++j)
                bP[st][j] = *(const short8*)(Bb + j * 16 * 1024 + cc * 32);
        }
    }

    // epilogue: 2 passes of 32 perm-cols
    float* Z = (float*)smem;                   // [128][36] f32 = 18432 B
#pragma unroll
    for (int p = 0; p < 2; ++p) {
        __syncthreads();
        if ((wave >> 1) == p) {
#pragma unroll
            for (int i = 0; i < 4; ++i)
#pragma unroll
                for (int j = 0; j < 2; ++j)
#pragma unroll
                    for (int r = 0; r < 4; ++r)
                        Z[(wr + i * 16 + lq * 4 + r) * 36 + (j * 16 + lr)] = acc[i][j][r];
        }
        __syncthreads();
#pragma unroll
        for (int rep = 0; rep < 4; ++rep) {
            int q = rep * 256 + tid;           // 0..1023
            int row = q >> 3, ui = q & 7;
            float4v z = *(const float4v*)&Z[row * 36 + ui * 4];
            gate_update(z, mtile * 128 + row, ntile * 16 + p * 8 + ui, t, false,
                        bias, nullptr, inputs, times, tau, sph, cst, hf_prev, hf_cur, hb_cur);
        }
    }
}

// ---------- FC + softmax: 16 rows/block, 4 rows/wave, batched coherent loads ----------
__device__ __forceinline__ void fc_step(char* smem, int fcid, int t,
    const float* __restrict__ h, float* __restrict__ out)
{
    const float* wT = (const float*)smem;              // [10][512]
    const float* bl = (const float*)(smem + 20480);    // [10]
    int wave = threadIdx.x >> 6, lane = threadIdx.x & 63;
    int rbase = fcid * 16 + wave * 4;
    float hv[4][8];
#pragma unroll
    for (int ri = 0; ri < 4; ++ri)
#pragma unroll
        for (int it = 0; it < 8; ++it) {
            unsigned v = __hip_atomic_load(
                (const unsigned*)&h[(size_t)(rbase + ri) * UDIM + it * 64 + lane],
                __ATOMIC_RELAXED, __HIP_MEMORY_SCOPE_AGENT);
            hv[ri][it] = __uint_as_float(v);
        }
#pragma unroll
    for (int ri = 0; ri < 4; ++ri) {
        int row = rbase + ri;
        float a[10];
#pragma unroll
        for (int c = 0; c < 10; ++c) a[c] = 0.0f;
#pragma unroll
        for (int it = 0; it < 8; ++it)
#pragma unroll
            for (int c = 0; c < 10; ++c) a[c] += hv[ri][it] * wT[c * 512 + it * 64 + lane];
#pragma unroll
        for (int c = 0; c < 10; ++c)
            for (int m = 32; m; m >>= 1) a[c] += __shfl_xor(a[c], m, 64);
        if (lane == 0) {
            float mx = -1e30f;
#pragma unroll
            for (int c = 0; c < 10; ++c) { a[c] += bl[c]; mx = fmaxf(mx, a[c]); }
            float sum = 0.0f;
#pragma unroll
            for (int c = 0; c < 10; ++c) { a[c] = __expf(a[c] - mx); sum += a[c]; }
            float inv = 1.0f / sum;
            float* op = &out[((size_t)row * TDIM + t) * 10];
#pragma unroll
            for (int c = 0; c < 10; ++c) op[c] = a[c] * inv;
        }
    }
}

// ---------- persistent diagonal-wavefront kernel, XCD-role-mapped ----------
__global__ __launch_bounds__(256, 2)
void persist_kernel(const float* __restrict__ inputs, const float* __restrict__ times,
                    const float* __restrict__ tau0, const float* __restrict__ sp0,
                    const float* __restrict__ tau1, const float* __restrict__ sp1,
                    const float* __restrict__ Wfc, const float* __restrict__ bfc,
                    char* __restrict__ ws, float* __restrict__ out)
{
    __shared__ __align__(16) char smem[34816];
    const int blk = blockIdx.x;
    const int tid = threadIdx.x;
    const int x = blk & 7;        // XCD id (dispatch heuristic; perf-only, not correctness)
    const int l = blk >> 3;       // 0..31 within XCD

    __hip_bfloat16* h0b[2] = {(__hip_bfloat16*)(ws + OFF_H0B), (__hip_bfloat16*)(ws + OFF_H0B + SZ_HB)};
    __hip_bfloat16* h1b[2] = {(__hip_bfloat16*)(ws + OFF_H1B), (__hip_bfloat16*)(ws + OFF_H1B + SZ_HB)};
    float* h0f[2] = {(float*)(ws + OFF_H0F), (float*)(ws + OFF_H0F + SZ_HF)};
    float* h1f[2] = {(float*)(ws + OFF_H1F), (float*)(ws + OFF_H1F + SZ_HF)};
    float* c0 = (float*)(ws + OFF_C0);
    float* c1 = (float*)(ws + OFF_C1);
    unsigned* bar = (unsigned*)(ws + OFF_BAR);
    const float* b0p = (const float*)(ws + OFF_B0P);
    const float* b1p = (const float*)(ws + OFF_B1P);
    const float* W0p = (const float*)(ws + OFF_W0P);
    const short* U0t = (const short*)(ws + OFF_U0T);
    const short* Wc  = (const short*)(ws + OFF_W1U1T);

    if (x >= 6 && l < 16) {
        // cache Wfc^T + bfc in LDS once
        float* wT = (float*)smem;
        float* bl = (float*)(smem + 20480);
        for (int i = tid; i < 5120; i += 256) {
            int c = i >> 9, k = i & 511;
            wT[i] = Wfc[(size_t)k * 10 + c];
        }
        if (tid < 10) bl[tid] = bfc[tid];
        __syncthreads();
    }

    for (int s = 0; s < TDIM + 2; ++s) {
        const int pA = (s + 1) & 1;   // parity holding step s-1 data
        const int pB = s & 1;         // parity holding step s-2 / receiving step s
        if (x < 2) {                  // l0: XCD 0-1, idx 0..63
            int idx = x * 32 + l;
            if (s < TDIM)
                l0_step(smem, idx >> 4, idx & 15, s,
                        (const short*)h0b[pA], U0t, b0p, W0p, inputs, times, tau0, sp0,
                        c0, h0f[pA], h0f[pB], h0b[pB]);
        } else if (x < 6) {           // l1: XCD 2-5, ntile-grouped for B L2 locality
            int nt = (x - 2) * 8 + (l >> 2);
            int mt = l & 3;
            if (s >= 1 && s <= TDIM)
                l1_step(smem, mt, nt, s - 1,
                        (const short*)h0b[pA], (const short*)h1b[pB], Wc, b1p,
                        inputs, times, tau1, sp1,
                        c1, h1f[pB], h1f[pA], h1b[pA]);
        } else if (l < 16) {          // fc: XCD 6-7, 32 blocks x 16 rows
            int fcid = (x - 6) * 16 + l;
            if (s >= 2)
                fc_step(smem, fcid, s - 2, h1f[pB], out);
        }
        gridbar(bar, (unsigned)(s + 1), blk);
    }
}

extern "C" void kernel_launch(void* const* d_in, const int* in_sizes, int n_in,
                              void* d_out, int out_size, void* d_ws, size_t ws_size,
                              hipStream_t stream) {
    const float* inputs = (const float*)d_in[0];
    const float* times  = (const float*)d_in[1];
    const float* W0   = (const float*)d_in[2];
    const float* U0   = (const float*)d_in[3];
    const float* b0   = (const float*)d_in[4];
    const float* tau0 = (const float*)d_in[5];
    const float* s0v  = (const float*)d_in[6];
    const float* W1   = (const float*)d_in[7];
    const float* U1   = (const float*)d_in[8];
    const float* b1   = (const float*)d_in[9];
    const float* tau1 = (const float*)d_in[10];
    const float* s1v  = (const float*)d_in[11];
    const float* Wfc  = (const float*)d_in[12];
    const float* bfc  = (const float*)d_in[13];
    float* out = (float*)d_out;
    char* ws = (char*)d_ws;

    hipMemsetAsync(ws + OFF_STATE, 0, STATE_BYTES, stream);
    prep_kernel<<<(NG * 1024) / 256, 256, 0, stream>>>(W0, U0, b0, W1, U1, b1, ws);
    persist_kernel<<<NBLK, 256, 0, stream>>>(inputs, times, tau0, s0v, tau1, s1v,
                                             Wfc, bfc, ws, out);
}

// Round 6
// 46369.772 us; speedup vs baseline: 2.7030x; 1.3574x over previous
//
#include <hip/hip_runtime.h>
#include <hip/hip_bf16.h>
#include <math.h>

#define BDIM 512
#define TDIM 1024
#define UDIM 512
#define NG   2048   // 4*U

typedef __attribute__((ext_vector_type(8))) short short8;
typedef __attribute__((ext_vector_type(4))) float float4v;

// ---------------- workspace layout ----------------
#define OFF_U0T   ((size_t)0)                       // bf16 [2048][512]  gate-interleaved, transposed
#define SZ_U0T    ((size_t)NG*UDIM*2)
#define OFF_W1U1T (OFF_U0T + SZ_U0T)                // bf16 [2048][1024] (W1 k<512, U1 k>=512)
#define SZ_W1U1T  ((size_t)NG*1024*2)
#define OFF_W0P   (OFF_W1U1T + SZ_W1U1T)            // f32 [3][2048] permuted
#define SZ_W0P    ((size_t)3*NG*4)
#define OFF_B0P   (OFF_W0P + SZ_W0P)
#define OFF_B1P   (OFF_B0P + (size_t)NG*4)
#define OFF_STATE (OFF_B1P + (size_t)NG*4)
#define SZ_HB     ((size_t)BDIM*UDIM*2)
#define SZ_HF     ((size_t)BDIM*UDIM*4)
#define OFF_H0B   (OFF_STATE)                       // bf16 x2 ping-pong
#define OFF_H1B   (OFF_H0B + 2*SZ_HB)
#define OFF_H0F   (OFF_H1B + 2*SZ_HB)               // f32 master x2
#define OFF_H1F   (OFF_H0F + 2*SZ_HF)
#define OFF_C0    (OFF_H1F + 2*SZ_HF)
#define OFF_C1    (OFF_C0 + SZ_HF)
#define OFF_BAR   (OFF_C1 + SZ_HF)                  // barrier: 8 group ctrs (128B apart) + root
#define SZ_BAR    ((size_t)(8*32+32)*4)
#define STATE_BYTES (OFF_BAR + SZ_BAR - OFF_STATE)

#define NBLK 256   // role by (blk&7): 0-1 l0(64), 2-5 l1(128), 6-7 fc(64)

// ---- hand-scheduled loads: coherent (sc0 sc1 -> LLC, same HW path r5 proved
// correct) and cached (weights, L2-resident). asm volatile keeps program order
// so manual vmcnt counting is exact; "+v" ties order waits vs MFMA consumers.
#define GLX4_C(dst, a) asm volatile("global_load_dwordx4 %0, %1, off sc0 sc1" : "=v"(dst) : "v"(a))
#define GLX4(dst, a)   asm volatile("global_load_dwordx4 %0, %1, off"         : "=v"(dst) : "v"(a))
#define GLD_C(dst, a)  asm volatile("global_load_dword %0, %1, off sc0 sc1"   : "=v"(dst) : "v"(a))

#define WAIT6(n, a0,a1,a2,a3,b0,b1) \
    asm volatile("s_waitcnt vmcnt(" #n ")" : "+v"(a0),"+v"(a1),"+v"(a2),"+v"(a3),"+v"(b0),"+v"(b1))
#define WAIT8(n, a0,a1,a2,a3,b0,b1,b2,b3) \
    asm volatile("s_waitcnt vmcnt(" #n ")" : "+v"(a0),"+v"(a1),"+v"(a2),"+v"(a3),"+v"(b0),"+v"(b1),"+v"(b2),"+v"(b3))

__device__ __forceinline__ float fsigm(float x) {
    return __builtin_amdgcn_rcpf(1.0f + __expf(-x));
}
__device__ __forceinline__ float ftanh(float x) {
    return 1.0f - 2.0f * __builtin_amdgcn_rcpf(1.0f + __expf(2.0f * x));
}

// ---------- weight prep (proven r1-r5): transpose + gate-interleave ----------
// n' = unit*4 + gate  <-  orig col = gate*512 + unit
__global__ void prep_kernel(const float* __restrict__ W0, const float* __restrict__ U0,
                            const float* __restrict__ b0, const float* __restrict__ W1,
                            const float* __restrict__ U1, const float* __restrict__ b1,
                            char* __restrict__ ws)
{
    int idx = blockIdx.x * 256 + threadIdx.x;   // 2048*1024 total
    int n = idx >> 10;
    int k = idx & 1023;
    int oc = (n & 3) * UDIM + (n >> 2);
    __hip_bfloat16* U0t = (__hip_bfloat16*)(ws + OFF_U0T);
    __hip_bfloat16* Wc  = (__hip_bfloat16*)(ws + OFF_W1U1T);
    float* W0p = (float*)(ws + OFF_W0P);
    float* b0p = (float*)(ws + OFF_B0P);
    float* b1p = (float*)(ws + OFF_B1P);
    if (k < 512) U0t[(size_t)n * 512 + k] = __float2bfloat16(U0[(size_t)k * NG + oc]);
    float wv = (k < 512) ? W1[(size_t)k * NG + oc] : U1[(size_t)(k - 512) * NG + oc];
    Wc[(size_t)n * 1024 + k] = __float2bfloat16(wv);
    if (k < 3) W0p[k * NG + n] = W0[(size_t)k * NG + oc];
    if (k == 0) { b0p[n] = b0[oc]; b1p[n] = b1[oc]; }
}

// ---------- grid barrier: release-only fence (wbl2, NO L2 invalidate) ----------
__device__ __forceinline__ void gridbar(unsigned* bar, unsigned phase, int blk) {
    __syncthreads();   // emits vmcnt(0): every wave's stores are at L2 before fence
    if (threadIdx.x == 0) {
        unsigned* gc   = bar + (blk & 7) * 32;
        unsigned* root = bar + 256;
        __builtin_amdgcn_fence(__ATOMIC_RELEASE, "agent");  // wbl2, no inv
        unsigned prev = __hip_atomic_fetch_add(gc, 1u, __ATOMIC_RELAXED, __HIP_MEMORY_SCOPE_AGENT);
        if (prev + 1u == phase * 32u)
            __hip_atomic_fetch_add(root, 1u, __ATOMIC_RELAXED, __HIP_MEMORY_SCOPE_AGENT);
        while (__hip_atomic_load(root, __ATOMIC_RELAXED, __HIP_MEMORY_SCOPE_AGENT) < phase * 8u) {}
        __atomic_signal_fence(__ATOMIC_ACQUIRE);
    }
    __syncthreads();
}

// ---------- fused LSTM gate + phased time-gate (one unit, one batch row) ----------
__device__ __forceinline__ void gate_update(float4v z, int b, int u, int t, bool isL0,
    const float* __restrict__ bias, const float* __restrict__ W0p,
    const float* __restrict__ inputs, const float* __restrict__ times,
    const float* __restrict__ tau, const float* __restrict__ sph,
    float* __restrict__ cst, const float* __restrict__ hf_prev,
    float* __restrict__ hf_cur, __hip_bfloat16* __restrict__ hb_cur)
{
    int pc = u * 4;
    float4v bz = *(const float4v*)&bias[pc];
    float zi = z[0] + bz[0], zf = z[1] + bz[1], zg = z[2] + bz[2], zo = z[3] + bz[3];
    if (isL0) {
        const float* xp = &inputs[((size_t)b * TDIM + t) * 3];
        float x0 = xp[0], x1 = xp[1], x2 = xp[2];
        float4v w0 = *(const float4v*)&W0p[pc];
        float4v w1 = *(const float4v*)&W0p[NG + pc];
        float4v w2 = *(const float4v*)&W0p[2 * NG + pc];
        zi += x0 * w0[0] + x1 * w1[0] + x2 * w2[0];
        zf += x0 * w0[1] + x1 * w1[1] + x2 * w2[1];
        zg += x0 * w0[2] + x1 * w1[2] + x2 * w2[2];
        zo += x0 * w0[3] + x1 * w1[3] + x2 * w2[3];
    }
    float ig = fsigm(zi), fg = fsigm(zf), gg = ftanh(zg), og = fsigm(zo);
    size_t su = (size_t)b * UDIM + u;
    float cp = cst[su];
    float cc = fg * cp + ig * gg;
    float hc = og * ftanh(cc);
    float tt = times[(size_t)b * TDIM + t];
    float x = (tt - sph[u]) / tau[u];
    float ph = x - floorf(x);                       // == mod(t-s,tau)/tau in [0,1)
    float kg = (ph < 0.025f) ? (ph * 40.0f)
             : (ph < 0.05f ? 2.0f - ph * 40.0f : 0.001f * ph);
    float cn = kg * cc + (1.0f - kg) * cp;
    float hn = kg * hc + (1.0f - kg) * hf_prev[su];
    cst[su] = cn;
    hf_cur[su] = hn;
    hb_cur[su] = __float2bfloat16(hn);
}

// ---------- layer-0: 128x128 tile, K=512; asm-pipelined, depth-4 ----------
__device__ __forceinline__ void l0_step(char* smem, int mtile, int ntile, int t,
    const short* __restrict__ A0, const short* __restrict__ Wt,
    const float* __restrict__ bias, const float* __restrict__ W0p,
    const float* __restrict__ inputs, const float* __restrict__ times,
    const float* __restrict__ tau, const float* __restrict__ sph,
    float* __restrict__ cst, const float* __restrict__ hf_prev,
    float* __restrict__ hf_cur, __hip_bfloat16* __restrict__ hb_cur)
{
    const int tid = threadIdx.x, wave = tid >> 6, lane = tid & 63;
    const int lr = lane & 15, lq = lane >> 4;
    const int wr = (wave & 1) * 64, wc = (wave >> 1) * 64;
    const short* Ab = A0 + (size_t)(mtile * 128 + wr + lr) * 512 + lq * 8;
    const short* Bb = Wt + (size_t)(ntile * 128 + wc + lr) * 512 + lq * 8;

    const float4v zero4 = {0.0f, 0.0f, 0.0f, 0.0f};
    float4v acc[4][4];
#pragma unroll
    for (int i = 0; i < 4; ++i)
#pragma unroll
        for (int j = 0; j < 4; ++j) acc[i][j] = zero4;

    short8 A[4][4], B[4][4];
#pragma unroll
    for (int st = 0; st < 4; ++st) {
#pragma unroll
        for (int i = 0; i < 4; ++i) GLX4_C(A[st][i], Ab + i * 16 * 512 + st * 32);
#pragma unroll
        for (int i = 0; i < 4; ++i) GLX4(B[st][i], Bb + i * 16 * 512 + st * 32);
    }
#pragma unroll
    for (int c = 0; c < 16; ++c) {
        const int st = c & 3;
        // exact wait: younger outstanding = 8 * min(3, 15-c)
        if (c <= 12)      WAIT8(24, A[st][0],A[st][1],A[st][2],A[st][3], B[st][0],B[st][1],B[st][2],B[st][3]);
        else if (c == 13) WAIT8(16, A[st][0],A[st][1],A[st][2],A[st][3], B[st][0],B[st][1],B[st][2],B[st][3]);
        else if (c == 14) WAIT8(8,  A[st][0],A[st][1],A[st][2],A[st][3], B[st][0],B[st][1],B[st][2],B[st][3]);
        else              WAIT8(0,  A[st][0],A[st][1],A[st][2],A[st][3], B[st][0],B[st][1],B[st][2],B[st][3]);
#pragma unroll
        for (int i = 0; i < 4; ++i)
#pragma unroll
            for (int j = 0; j < 4; ++j)
                acc[i][j] = __builtin_amdgcn_mfma_f32_16x16x32_bf16(A[st][i], B[st][j], acc[i][j], 0, 0, 0);
        if (c + 4 < 16) {
            const int kk = (c + 4) * 32;
#pragma unroll
            for (int i = 0; i < 4; ++i) GLX4_C(A[st][i], Ab + i * 16 * 512 + kk);
#pragma unroll
            for (int i = 0; i < 4; ++i) GLX4(B[st][i], Bb + i * 16 * 512 + kk);
        }
    }

    // epilogue: 2 passes of 64 perm-cols via LDS transpose
    float* Z = (float*)smem;                   // [128][68] f32 = 34816 B
#pragma unroll
    for (int p = 0; p < 2; ++p) {
        __syncthreads();
        if ((wave >> 1) == p) {
#pragma unroll
            for (int i = 0; i < 4; ++i)
#pragma unroll
                for (int j = 0; j < 4; ++j)
#pragma unroll
                    for (int r = 0; r < 4; ++r)
                        Z[(wr + i * 16 + lq * 4 + r) * 68 + (j * 16 + lr)] = acc[i][j][r];
        }
        __syncthreads();
#pragma unroll
        for (int rep = 0; rep < 8; ++rep) {
            int q = rep * 256 + tid;           // 0..2047
            int row = q >> 4, ui = q & 15;
            float4v z = *(const float4v*)&Z[row * 68 + ui * 4];
            gate_update(z, mtile * 128 + row, ntile * 32 + p * 16 + ui, t, true,
                        bias, W0p, inputs, times, tau, sph, cst, hf_prev, hf_cur, hb_cur);
        }
    }
}

// ---------- layer-1: 128x64 tile, K=1024 (A=[h0|h1]); asm-pipelined, depth-4 ----------
__device__ __forceinline__ void l1_step(char* smem, int mtile, int ntile, int t,
    const short* __restrict__ A0, const short* __restrict__ A1,
    const short* __restrict__ Wt, const float* __restrict__ bias,
    const float* __restrict__ inputs, const float* __restrict__ times,
    const float* __restrict__ tau, const float* __restrict__ sph,
    float* __restrict__ cst, const float* __restrict__ hf_prev,
    float* __restrict__ hf_cur, __hip_bfloat16* __restrict__ hb_cur)
{
    const int tid = threadIdx.x, wave = tid >> 6, lane = tid & 63;
    const int lr = lane & 15, lq = lane >> 4;
    const int wr = (wave & 1) * 64, wc = (wave >> 1) * 32;
    const short* Ab0 = A0 + (size_t)(mtile * 128 + wr + lr) * 512 + lq * 8;
    const short* Ab1 = A1 + (size_t)(mtile * 128 + wr + lr) * 512 + lq * 8;
    const short* Bb  = Wt + (size_t)(ntile * 64 + wc + lr) * 1024 + lq * 8;

    const float4v zero4 = {0.0f, 0.0f, 0.0f, 0.0f};
    float4v acc[4][2];
#pragma unroll
    for (int i = 0; i < 4; ++i)
#pragma unroll
        for (int j = 0; j < 2; ++j) acc[i][j] = zero4;

    short8 A[4][4], B[4][2];
#pragma unroll
    for (int st = 0; st < 4; ++st) {
#pragma unroll
        for (int i = 0; i < 4; ++i) GLX4_C(A[st][i], Ab0 + i * 16 * 512 + st * 32);
#pragma unroll
        for (int j = 0; j < 2; ++j) GLX4(B[st][j], Bb + j * 16 * 1024 + st * 32);
    }
#pragma unroll
    for (int c = 0; c < 32; ++c) {
        const int st = c & 3;
        // exact wait: younger outstanding = 6 * min(3, 31-c)
        if (c <= 28)      WAIT6(18, A[st][0],A[st][1],A[st][2],A[st][3], B[st][0],B[st][1]);
        else if (c == 29) WAIT6(12, A[st][0],A[st][1],A[st][2],A[st][3], B[st][0],B[st][1]);
        else if (c == 30) WAIT6(6,  A[st][0],A[st][1],A[st][2],A[st][3], B[st][0],B[st][1]);
        else              WAIT6(0,  A[st][0],A[st][1],A[st][2],A[st][3], B[st][0],B[st][1]);
#pragma unroll
        for (int i = 0; i < 4; ++i)
#pragma unroll
            for (int j = 0; j < 2; ++j)
                acc[i][j] = __builtin_amdgcn_mfma_f32_16x16x32_bf16(A[st][i], B[st][j], acc[i][j], 0, 0, 0);
        if (c + 4 < 32) {
            const int cc = c + 4;
            const short* Abase = (cc < 16) ? Ab0 : Ab1;
            const int kk = (cc & 15) * 32;
#pragma unroll
            for (int i = 0; i < 4; ++i) GLX4_C(A[st][i], Abase + i * 16 * 512 + kk);
#pragma unroll
            for (int j = 0; j < 2; ++j) GLX4(B[st][j], Bb + j * 16 * 1024 + cc * 32);
        }
    }

    // epilogue: 2 passes of 32 perm-cols
    float* Z = (float*)smem;                   // [128][36] f32 = 18432 B
#pragma unroll
    for (int p = 0; p < 2; ++p) {
        __syncthreads();
        if ((wave >> 1) == p) {
#pragma unroll
            for (int i = 0; i < 4; ++i)
#pragma unroll
                for (int j = 0; j < 2; ++j)
#pragma unroll
                    for (int r = 0; r < 4; ++r)
                        Z[(wr + i * 16 + lq * 4 + r) * 36 + (j * 16 + lr)] = acc[i][j][r];
        }
        __syncthreads();
#pragma unroll
        for (int rep = 0; rep < 4; ++rep) {
            int q = rep * 256 + tid;           // 0..1023
            int row = q >> 3, ui = q & 7;
            float4v z = *(const float4v*)&Z[row * 36 + ui * 4];
            gate_update(z, mtile * 128 + row, ntile * 16 + p * 8 + ui, t, false,
                        bias, nullptr, inputs, times, tau, sph, cst, hf_prev, hf_cur, hb_cur);
        }
    }
}

// ---------- FC + softmax: 8 rows/block (64 blocks), asm-pipelined loads ----------
__device__ __forceinline__ void fc_step(char* smem, int fcid, int t,
    const float* __restrict__ h, float* __restrict__ out)
{
    const float* wT = (const float*)smem;              // [10][512]
    const float* bl = (const float*)(smem + 20480);    // [10]
    int wave = threadIdx.x >> 6, lane = threadIdx.x & 63;
    int rbase = fcid * 8 + wave * 2;
    float hv[2][8];
#pragma unroll
    for (int ri = 0; ri < 2; ++ri)
#pragma unroll
        for (int it = 0; it < 8; ++it)
            GLD_C(hv[ri][it], &h[(size_t)(rbase + ri) * UDIM + it * 64 + lane]);
#pragma unroll
    for (int ri = 0; ri < 2; ++ri) {
        if (ri == 0) WAIT8(8, hv[0][0],hv[0][1],hv[0][2],hv[0][3],hv[0][4],hv[0][5],hv[0][6],hv[0][7]);
        else         WAIT8(0, hv[1][0],hv[1][1],hv[1][2],hv[1][3],hv[1][4],hv[1][5],hv[1][6],hv[1][7]);
        int row = rbase + ri;
        float a[10];
#pragma unroll
        for (int c = 0; c < 10; ++c) a[c] = 0.0f;
#pragma unroll
        for (int it = 0; it < 8; ++it)
#pragma unroll
            for (int c = 0; c < 10; ++c) a[c] += hv[ri][it] * wT[c * 512 + it * 64 + lane];
#pragma unroll
        for (int c = 0; c < 10; ++c)
            for (int m = 32; m; m >>= 1) a[c] += __shfl_xor(a[c], m, 64);
        if (lane == 0) {
            float mx = -1e30f;
#pragma unroll
            for (int c = 0; c < 10; ++c) { a[c] += bl[c]; mx = fmaxf(mx, a[c]); }
            float sum = 0.0f;
#pragma unroll
            for (int c = 0; c < 10; ++c) { a[c] = __expf(a[c] - mx); sum += a[c]; }
            float inv = 1.0f / sum;
            float* op = &out[((size_t)row * TDIM + t) * 10];
#pragma unroll
            for (int c = 0; c < 10; ++c) op[c] = a[c] * inv;
        }
    }
}

// ---------- persistent diagonal-wavefront kernel ----------
__global__ __launch_bounds__(256, 1)
void persist_kernel(const float* __restrict__ inputs, const float* __restrict__ times,
                    const float* __restrict__ tau0, const float* __restrict__ sp0,
                    const float* __restrict__ tau1, const float* __restrict__ sp1,
                    const float* __restrict__ Wfc, const float* __restrict__ bfc,
                    char* __restrict__ ws, float* __restrict__ out)
{
    __shared__ __align__(16) char smem[34816];
    const int blk = blockIdx.x;
    const int tid = threadIdx.x;
    const int x = blk & 7;        // XCD id heuristic (perf-only; coherence never depends on it)
    const int l = blk >> 3;       // 0..31 within XCD

    __hip_bfloat16* h0b[2] = {(__hip_bfloat16*)(ws + OFF_H0B), (__hip_bfloat16*)(ws + OFF_H0B + SZ_HB)};
    __hip_bfloat16* h1b[2] = {(__hip_bfloat16*)(ws + OFF_H1B), (__hip_bfloat16*)(ws + OFF_H1B + SZ_HB)};
    float* h0f[2] = {(float*)(ws + OFF_H0F), (float*)(ws + OFF_H0F + SZ_HF)};
    float* h1f[2] = {(float*)(ws + OFF_H1F), (float*)(ws + OFF_H1F + SZ_HF)};
    float* c0 = (float*)(ws + OFF_C0);
    float* c1 = (float*)(ws + OFF_C1);
    unsigned* bar = (unsigned*)(ws + OFF_BAR);
    const float* b0p = (const float*)(ws + OFF_B0P);
    const float* b1p = (const float*)(ws + OFF_B1P);
    const float* W0p = (const float*)(ws + OFF_W0P);
    const short* U0t = (const short*)(ws + OFF_U0T);
    const short* Wc  = (const short*)(ws + OFF_W1U1T);

    if (x >= 6) {
        // cache Wfc^T + bfc in LDS once
        float* wT = (float*)smem;
        float* bl = (float*)(smem + 20480);
        for (int i = tid; i < 5120; i += 256) {
            int c = i >> 9, k = i & 511;
            wT[i] = Wfc[(size_t)k * 10 + c];
        }
        if (tid < 10) bl[tid] = bfc[tid];
        __syncthreads();
    }

    for (int s = 0; s < TDIM + 2; ++s) {
        const int pA = (s + 1) & 1;   // parity holding step s-1 data
        const int pB = s & 1;         // parity holding step s-2 / receiving step s
        if (x < 2) {                  // l0: 64 blocks
            int idx = x * 32 + l;
            if (s < TDIM)
                l0_step(smem, idx >> 4, idx & 15, s,
                        (const short*)h0b[pA], U0t, b0p, W0p, inputs, times, tau0, sp0,
                        c0, h0f[pA], h0f[pB], h0b[pB]);
        } else if (x < 6) {           // l1: 128 blocks, ntile-grouped
            int nt = (x - 2) * 8 + (l >> 2);
            int mt = l & 3;
            if (s >= 1 && s <= TDIM)
                l1_step(smem, mt, nt, s - 1,
                        (const short*)h0b[pA], (const short*)h1b[pB], Wc, b1p,
                        inputs, times, tau1, sp1,
                        c1, h1f[pB], h1f[pA], h1b[pA]);
        } else {                      // fc: 64 blocks x 8 rows
            int fcid = (x - 6) * 32 + l;
            if (s >= 2)
                fc_step(smem, fcid, s - 2, h1f[pB], out);
        }
        gridbar(bar, (unsigned)(s + 1), blk);
    }
}

extern "C" void kernel_launch(void* const* d_in, const int* in_sizes, int n_in,
                              void* d_out, int out_size, void* d_ws, size_t ws_size,
                              hipStream_t stream) {
    const float* inputs = (const float*)d_in[0];
    const float* times  = (const float*)d_in[1];
    const float* W0   = (const float*)d_in[2];
    const float* U0   = (const float*)d_in[3];
    const float* b0   = (const float*)d_in[4];
    const float* tau0 = (const float*)d_in[5];
    const float* s0v  = (const float*)d_in[6];
    const float* W1   = (const float*)d_in[7];
    const float* U1   = (const float*)d_in[8];
    const float* b1   = (const float*)d_in[9];
    const float* tau1 = (const float*)d_in[10];
    const float* s1v  = (const float*)d_in[11];
    const float* Wfc  = (const float*)d_in[12];
    const float* bfc  = (const float*)d_in[13];
    float* out = (float*)d_out;
    char* ws = (char*)d_ws;

    hipMemsetAsync(ws + OFF_STATE, 0, STATE_BYTES, stream);
    prep_kernel<<<(NG * 1024) / 256, 256, 0, stream>>>(W0, U0, b0, W1, U1, b1, ws);
    persist_kernel<<<NBLK, 256, 0, stream>>>(inputs, times, tau0, s0v, tau1, s1v,
                                             Wfc, bfc, ws, out);
}